// Round 21
// baseline (157.023 us; speedup 1.0000x reference)
//
#include <hip/hip_runtime.h>
#include <hip/hip_fp16.h>

#define NV    6890
#define NQ    32768
#define DF    64
#define NW    16      // waves per knn block
#define CHUNK 431     // ceil(NV/16)
#define SAMP  32      // sample vertices per wave (16*32 = 512 total)
#define CAPQ  20

typedef _Float16 v8h  __attribute__((ext_vector_type(8)));
typedef float    f32x4 __attribute__((ext_vector_type(4)));
typedef unsigned int       u32;
typedef unsigned long long u64;
typedef unsigned short     u16;

// ---- workspace layout (bytes) ----
static constexpr size_t VTX4_OFF  = 0;                               // float4[6912]
static constexpr size_t KIDX_OFF  = 110592;                          // int[NQ*8]
static constexpr size_t KW_OFF    = KIDX_OFF + (size_t)NQ * 8 * 4;   // float[NQ*8]
static constexpr size_t WFRAG_OFF = KW_OFF + (size_t)NQ * 8 * 4;     // f16[53248]

__device__ __forceinline__ u32 monof(float s) {
    u32 u = __float_as_uint(s);
    return (u & 0x80000000u) ? ~u : (u | 0x80000000u);
}

// Force an index into an SGPR so vtx4[.] compiles to s_load (wave-uniform by
// construction: the value is identical across lanes when called).
__device__ __forceinline__ int sgpr(int j) {
    return __builtin_amdgcn_readfirstlane(j);
}

// distance-only sorted top-8 insert (ascending), ~24 VALU.
#define DINSERT(sv) do {                                               \
    bool c0 = (sv) < dbest[0], c1 = (sv) < dbest[1],                   \
         c2 = (sv) < dbest[2], c3 = (sv) < dbest[3],                   \
         c4 = (sv) < dbest[4], c5 = (sv) < dbest[5],                   \
         c6 = (sv) < dbest[6], c7 = (sv) < dbest[7];                   \
    dbest[7] = c7 ? (c6 ? dbest[6] : (sv)) : dbest[7];                 \
    dbest[6] = c6 ? (c5 ? dbest[5] : (sv)) : dbest[6];                 \
    dbest[5] = c5 ? (c4 ? dbest[4] : (sv)) : dbest[5];                 \
    dbest[4] = c4 ? (c3 ? dbest[3] : (sv)) : dbest[4];                 \
    dbest[3] = c3 ? (c2 ? dbest[2] : (sv)) : dbest[3];                 \
    dbest[2] = c2 ? (c1 ? dbest[1] : (sv)) : dbest[2];                 \
    dbest[1] = c1 ? (c0 ? dbest[0] : (sv)) : dbest[1];                 \
    dbest[0] = c0 ? (sv) : dbest[0];                                   \
} while (0)

// u64 sorted top-8 insert (ascending). Compares precomputed; uses OLD values.
#define KINSERT(nk) do {                                  \
    bool c0 = (nk) < key[0], c1 = (nk) < key[1],          \
         c2 = (nk) < key[2], c3 = (nk) < key[3],          \
         c4 = (nk) < key[4], c5 = (nk) < key[5],          \
         c6 = (nk) < key[6], c7 = (nk) < key[7];          \
    key[7] = c7 ? (c6 ? key[6] : (nk)) : key[7];          \
    key[6] = c6 ? (c5 ? key[5] : (nk)) : key[6];          \
    key[5] = c5 ? (c4 ? key[4] : (nk)) : key[5];          \
    key[4] = c4 ? (c3 ? key[3] : (nk)) : key[4];          \
    key[3] = c3 ? (c2 ? key[2] : (nk)) : key[3];          \
    key[2] = c2 ? (c1 ? key[1] : (nk)) : key[2];          \
    key[1] = c1 ? (c0 ? key[0] : (nk)) : key[1];          \
    key[0] = c0 ? (nk) : key[0];                          \
} while (0)

#define TRYQ(sv, jv) do {                                                      \
    if ((sv) <= T) {                                                           \
        if (cnt < CAPQ) { qq[w][l][cnt] = (u16)(jv); ++cnt; }                  \
        else {                                                                 \
            u64 nk = ((u64)monof(sv) << 16) | (u64)(jv);                       \
            if (nk < key[7]) { KINSERT(nk); }                                  \
        }                                                                      \
    }                                                                          \
} while (0)

// prep: pack vertices {x,y,z,0.5|v|^2} only (wfrag fused into knn grid).
__global__ void prep_kernel(const float* __restrict__ vtx, float4* __restrict__ vtx4) {
    int i = blockIdx.x * 256 + threadIdx.x;
    if (i < NV) {
        float x = vtx[i * 3 + 0], y = vtx[i * 3 + 1], z = vtx[i * 3 + 2];
        vtx4[i] = make_float4(x, y, z, 0.5f * (x * x + y * y + z * z));
    }
}

__device__ __forceinline__ float vdist(const float4 v, float nqx, float nqy, float nqz) {
    float s = fmaf(nqx, v.x, v.w);
    s = fmaf(nqy, v.y, s);
    return fmaf(nqz, v.z, s);
}

// Exact two-phase KNN = R20 champion (SGPR-forced scalar addressing), unchanged.
// Blocks >= 512 do the wfrag swizzle (CT-MAJOR tile order: t = ct*KS + kt, so
// per-ct-group tile ranges are contiguous for the mlp LDS staging).
__global__ __launch_bounds__(1024, 8) void knn_kernel(const float4* __restrict__ vtx4,
                                                      const float* __restrict__ qpts,
                                                      int* __restrict__ kidx,
                                                      float* __restrict__ kw,
                                                      const float* __restrict__ W0,
                                                      const float* __restrict__ W1,
                                                      const float* __restrict__ W2,
                                                      const float* __restrict__ W3,
                                                      _Float16* __restrict__ wfrag) {
    if (blockIdx.x >= NQ / 64) {
        // fused weight-fragment swizzle, ct-major: within a layer, tile
        // t = ct*KS + kt; elem = t*512 + lane*8 + jj; k = kt*32+(lane>>4)*8+jj,
        // col = ct*16+(lane&15).
        int e = (blockIdx.x - NQ / 64) * 1024 + threadIdx.x;   // 0..53247
        const float* W; int base, C, KD, KS;
        if      (e < 12288) { W = W0; base = 0;     C = 128; KD = 67;  KS = 3; }
        else if (e < 28672) { W = W1; base = 12288; C = 128; KD = 128; KS = 4; }
        else if (e < 45056) { W = W2; base = 28672; C = 128; KD = 128; KS = 4; }
        else                { W = W3; base = 45056; C = 64;  KD = 128; KS = 4; }
        int le = e - base;
        int t = le >> 9, r = le & 511;
        int lane = r >> 3, jj = r & 7;
        int ct = t / KS, kt = t % KS;
        int k = kt * 32 + (lane >> 4) * 8 + jj;
        int col = ct * 16 + (lane & 15);
        float v = (k < KD) ? W[k * C + col] : 0.0f;
        wfrag[e] = (_Float16)v;
        return;
    }

    __shared__ u64   kbuf[8][64][9];        // 36864 B; aliased f32[16][64][9] in phase A
    __shared__ u16   qq[NW][64][CAPQ];      // 40960 B
    __shared__ float Tbc[64];
    float (*fbuf)[64][9] = (float (*)[64][9])kbuf;

    const int tid = threadIdx.x, w = tid >> 6, l = tid & 63;
    const int m = blockIdx.x * 64 + l;
    const float qx = qpts[m * 3 + 0], qy = qpts[m * 3 + 1], qz = qpts[m * 3 + 2];
    const float nqx = -qx, nqy = -qy, nqz = -qz;

    // ---- phase A: per-wave 32-vertex sample, distance-only top-8 ----
    float dbest[8];
#pragma unroll
    for (int i = 0; i < 8; ++i) dbest[i] = 3.0e38f;
    {
        const int s0 = sgpr(w * SAMP);
#pragma unroll 4
        for (int j = 0; j < SAMP; ++j) {
            float s = vdist(vtx4[s0 + j], nqx, nqy, nqz);   // SGPR addr -> s_load
            DINSERT(s);
        }
    }
#pragma unroll
    for (int i = 0; i < 8; ++i) fbuf[w][l][i] = dbest[i];
    __syncthreads();

    // ---- T tree-reduce: read [st,2st) slots, merge, write [0,st) ----
#pragma unroll 1
    for (int st = 8; st >= 1; st >>= 1) {
        if (w < st) {
#pragma unroll
            for (int e = 0; e < 8; ++e) {
                float s = fbuf[w + st][l][e];
                if (s < dbest[7]) { DINSERT(s); }
            }
            if (st > 1) {
#pragma unroll
                for (int i = 0; i < 8; ++i) fbuf[w][l][i] = dbest[i];
            }
        }
        __syncthreads();
    }
    if (w == 0) Tbc[l] = dbest[7];
    __syncthreads();
    const float T = Tbc[l];

    // ---- scan: full chunk, unroll-4, SGPR-addressed loads ----
    u64 key[8];
#pragma unroll
    for (int i = 0; i < 8; ++i) key[i] = ~0ull;
    u32 cnt = 0;
    const int j0 = sgpr(w * CHUNK);
    const int j1 = sgpr((w * CHUNK + CHUNK < NV) ? w * CHUNK + CHUNK : NV);
    {
        int j = j0;
#pragma unroll 1
        for (; j + 4 <= j1; j += 4) {
            const int jb = sgpr(j);
            float4 v0 = vtx4[jb + 0], v1 = vtx4[jb + 1];
            float4 v2 = vtx4[jb + 2], v3 = vtx4[jb + 3];
            float s0 = vdist(v0, nqx, nqy, nqz);
            float s1 = vdist(v1, nqx, nqy, nqz);
            float s2 = vdist(v2, nqx, nqy, nqz);
            float s3 = vdist(v3, nqx, nqy, nqz);
            TRYQ(s0, jb + 0); TRYQ(s1, jb + 1); TRYQ(s2, jb + 2); TRYQ(s3, jb + 3);
        }
        for (; j < j1; ++j) {
            const int jb = sgpr(j);
            float s = vdist(vtx4[jb], nqx, nqy, nqz);
            TRYQ(s, jb);
        }
    }

    // ---- drain queue in batches of 4 (exact keys, per-lane loads) ----
#pragma unroll 1
    for (int b = 0; b < CAPQ; b += 4) {
        if (!__any(cnt > (u32)b)) break;
        u32 jj[4]; float4 vv[4];
#pragma unroll
        for (int t = 0; t < 4; ++t) {
            u32 qi = ((u32)(b + t) < cnt) ? (u32)qq[w][l][b + t] : 0u;
            jj[t] = qi; vv[t] = vtx4[qi];
        }
#pragma unroll
        for (int t = 0; t < 4; ++t) {
            float s = vdist(vv[t], nqx, nqy, nqz);
            u64 nk = ((u64)monof(s) << 16) | (u64)jj[t];
            nk = ((u32)(b + t) < cnt) ? nk : ~0ull;
            if (nk < key[7]) { KINSERT(nk); }
        }
    }

    // ---- tree merge of 16 key lists: publish [st,2st) -> merge on [0,st) ----
#pragma unroll 1
    for (int st = 8; st >= 1; st >>= 1) {
        if (w >= st && w < 2 * st) {
#pragma unroll
            for (int i = 0; i < 8; ++i) kbuf[w - st][l][i] = key[i];
        }
        __syncthreads();
        if (w < st) {
#pragma unroll
            for (int e = 0; e < 8; ++e) {
                u64 nk = kbuf[w][l][e];
                if (nk < key[7]) { KINSERT(nk); }
            }
        }
        __syncthreads();
    }

    // ---- wave 0: weights + output ----
    if (w == 0) {
        float q2 = fmaf(qx, qx, fmaf(qy, qy, qz * qz));
        float inv[8], ssum = 0.0f;
        int idx8[8];
#pragma unroll
        for (int i = 0; i < 8; ++i) {
            u32 us = (u32)(key[i] >> 16);
            u32 uo = (us & 0x80000000u) ? (us & 0x7FFFFFFFu) : ~us;
            float s = __uint_as_float(uo);
            float dd = fmaf(2.0f, s, q2);
            float d = sqrtf(fmaxf(dd, 0.0f)) + 1e-9f;
            inv[i] = 1.0f / d; ssum += inv[i];
            idx8[i] = (int)(key[i] & 0xFFFFull);
        }
        float rs = 1.0f / ssum;
#pragma unroll
        for (int i = 0; i < 8; ++i) {
            kidx[m * 8 + i] = idx8[i];
            kw[m * 8 + i]   = inv[i] * rs;
        }
    }
}

// Stage NT contiguous 1KB tiles from global wfrag into the 16KB LDS region.
// 256 threads x v8h(16B), coalesced; NT*64/256 = NT/4 passes (loop count = p<NT*64 step 256).
__device__ __forceinline__ void stage_w(_Float16* wst, const _Float16* __restrict__ src,
                                        int nt, int tid) {
    const v8h* s = (const v8h*)src;
    v8h*       d = (v8h*)wst;
    for (int p = tid; p < nt * 64; p += 256) d[p] = s[p];
}

// One 8-col-group MLP layer, weights staged in LDS per 4-ct half (shared by all
// 4 waves -> 4x less L2 traffic). acc held across halves (static indices).
// Staged tile index for half at c0: (c*KSTEPS + ks), tiles contiguous (ct-major).
template <int KSTEPS, bool RELU>
__device__ __forceinline__ void mlp_layer8(_Float16 (*buf)[136], _Float16* wst,
                                           const _Float16* __restrict__ frag,
                                           const float* __restrict__ bias,
                                           int w, int l, int tid) {
    const int cl = l & 15, gl = l >> 4;
    f32x4 acc[2][8];
#pragma unroll
    for (int ct = 0; ct < 8; ++ct) {
        float bv = bias[ct * 16 + cl];
        acc[0][ct] = (f32x4){bv, bv, bv, bv};
        acc[1][ct] = (f32x4){bv, bv, bv, bv};
    }
    // ---- half A: ct 0..3 (tiles [0, 4*KSTEPS)) ----
    __syncthreads();
    stage_w(wst, frag, 4 * KSTEPS, tid);
    __syncthreads();
#pragma unroll 1
    for (int ks = 0; ks < KSTEPS; ++ks) {
        v8h a0 = *(const v8h*)&buf[w * 32 + cl][ks * 32 + gl * 8];
        v8h a1 = *(const v8h*)&buf[w * 32 + 16 + cl][ks * 32 + gl * 8];
#pragma unroll
        for (int c = 0; c < 4; ++c) {
            v8h bf = *(const v8h*)&wst[(c * KSTEPS + ks) * 512 + l * 8];
            acc[0][c] = __builtin_amdgcn_mfma_f32_16x16x32_f16(a0, bf, acc[0][c], 0, 0, 0);
            acc[1][c] = __builtin_amdgcn_mfma_f32_16x16x32_f16(a1, bf, acc[1][c], 0, 0, 0);
        }
    }
    // ---- half B: ct 4..7 (tiles [4*KSTEPS, 8*KSTEPS)) ----
    __syncthreads();
    stage_w(wst, frag + (size_t)4 * KSTEPS * 512, 4 * KSTEPS, tid);
    __syncthreads();
#pragma unroll 1
    for (int ks = 0; ks < KSTEPS; ++ks) {
        v8h a0 = *(const v8h*)&buf[w * 32 + cl][ks * 32 + gl * 8];
        v8h a1 = *(const v8h*)&buf[w * 32 + 16 + cl][ks * 32 + gl * 8];
#pragma unroll
        for (int c = 0; c < 4; ++c) {
            v8h bf = *(const v8h*)&wst[(c * KSTEPS + ks) * 512 + l * 8];
            acc[0][4 + c] = __builtin_amdgcn_mfma_f32_16x16x32_f16(a0, bf, acc[0][4 + c], 0, 0, 0);
            acc[1][4 + c] = __builtin_amdgcn_mfma_f32_16x16x32_f16(a1, bf, acc[1][4 + c], 0, 0, 0);
        }
    }
    // ---- write (wave-private rows; C/D layout m89: row=(l>>4)*4+j, col=l&15) ----
#pragma unroll
    for (int rt = 0; rt < 2; ++rt)
#pragma unroll
        for (int ct = 0; ct < 8; ++ct)
#pragma unroll
            for (int j = 0; j < 4; ++j) {
                float v = acc[rt][ct][j];
                if (RELU) v = fmaxf(v, 0.0f);
                buf[w * 32 + rt * 16 + gl * 4 + j][ct * 16 + cl] = (_Float16)v;
            }
}

// Block = 128 rows (16 queries x 8 NB), 4 waves. Weights LDS-staged per layer.
__global__ __launch_bounds__(256, 3) void mlp_kernel(
    const float* __restrict__ vf, const float4* __restrict__ vtx4,
    const float* __restrict__ qpts,
    const int* __restrict__ kidx, const float* __restrict__ kw,
    const _Float16* __restrict__ wfrag,
    const float* __restrict__ b0, const float* __restrict__ b1,
    const float* __restrict__ b2, const float* __restrict__ b3,
    float* __restrict__ out) {
    __shared__ _Float16 buf[128][136];   // 34816 B
    __shared__ _Float16 wst[8192];       // 16384 B weight stage (51.2 KB total)
    const int tid = threadIdx.x, w = tid >> 6, l = tid & 63;
    {
        int h = l & 1;
        int lrow = w * 32 + (l >> 1);
        int grow = blockIdx.x * 128 + lrow;
        int q = grow >> 3;
        int idx = kidx[grow];
        const float4* src = (const float4*)(vf + (size_t)idx * DF) + h * 8;
#pragma unroll
        for (int t = 0; t < 4; ++t) {
            float4 a = src[2 * t], b = src[2 * t + 1];
            v8h pk = {(_Float16)a.x, (_Float16)a.y, (_Float16)a.z, (_Float16)a.w,
                      (_Float16)b.x, (_Float16)b.y, (_Float16)b.z, (_Float16)b.w};
            *(v8h*)&buf[lrow][h * 32 + t * 8] = pk;
        }
        v8h zz = {0, 0, 0, 0, 0, 0, 0, 0};
        if (h == 0) {
            float4 v = vtx4[idx];
            float qx = qpts[q * 3 + 0], qy = qpts[q * 3 + 1], qz = qpts[q * 3 + 2];
            v8h d = {(_Float16)(qx - v.x), (_Float16)(qy - v.y), (_Float16)(qz - v.z),
                     0, 0, 0, 0, 0};
            *(v8h*)&buf[lrow][64] = d;
            *(v8h*)&buf[lrow][88] = zz;
        } else {
            *(v8h*)&buf[lrow][72] = zz;
            *(v8h*)&buf[lrow][80] = zz;
        }
    }

    mlp_layer8<3, true>(buf, wst, wfrag + 0,     b0, w, l, tid);
    mlp_layer8<4, true>(buf, wst, wfrag + 12288, b1, w, l, tid);
    mlp_layer8<4, true>(buf, wst, wfrag + 28672, b2, w, l, tid);

    // ---- layer 3 (K=128 -> 64 cols), single 16KB stage + weighting + reduce ----
    {
        const int cl = l & 15, gl = l >> 4;
        f32x4 acc[2][4];
#pragma unroll
        for (int ct = 0; ct < 4; ++ct) {
            float bv = b3[ct * 16 + cl];
#pragma unroll
            for (int rt = 0; rt < 2; ++rt) acc[rt][ct] = (f32x4){bv, bv, bv, bv};
        }
        __syncthreads();
        stage_w(wst, wfrag + 45056, 16, tid);
        __syncthreads();
#pragma unroll 1
        for (int ks = 0; ks < 4; ++ks) {
            v8h a0 = *(const v8h*)&buf[w * 32 + cl][ks * 32 + gl * 8];
            v8h a1 = *(const v8h*)&buf[w * 32 + 16 + cl][ks * 32 + gl * 8];
#pragma unroll
            for (int ct = 0; ct < 4; ++ct) {
                v8h bf = *(const v8h*)&wst[(ct * 4 + ks) * 512 + l * 8];
                acc[0][ct] = __builtin_amdgcn_mfma_f32_16x16x32_f16(a0, bf, acc[0][ct], 0, 0, 0);
                acc[1][ct] = __builtin_amdgcn_mfma_f32_16x16x32_f16(a1, bf, acc[1][ct], 0, 0, 0);
            }
        }
        int GRbase = blockIdx.x * 128 + w * 32;
#pragma unroll
        for (int rt = 0; rt < 2; ++rt) {
            int r4 = GRbase + rt * 16 + gl * 4;
            float4 kv = *(const float4*)&kw[r4];
#pragma unroll
            for (int ct = 0; ct < 4; ++ct) {
                float v = acc[rt][ct][0] * kv.x + acc[rt][ct][1] * kv.y +
                          acc[rt][ct][2] * kv.z + acc[rt][ct][3] * kv.w;
                v += __shfl_xor(v, 16);
                if ((gl & 1) == 0) {
                    int q = (GRbase + rt * 16 + ((gl == 2) ? 8 : 0)) >> 3;
                    out[(size_t)q * 64 + ct * 16 + cl] = v;
                }
            }
        }
    }
}

extern "C" void kernel_launch(void* const* d_in, const int* in_sizes, int n_in,
                              void* d_out, int out_size, void* d_ws, size_t ws_size,
                              hipStream_t stream) {
    const float* vtx = (const float*)d_in[0];
    const float* vf  = (const float*)d_in[1];
    const float* qp  = (const float*)d_in[2];
    const float* W0  = (const float*)d_in[3];
    const float* b0  = (const float*)d_in[4];
    const float* W1  = (const float*)d_in[5];
    const float* b1  = (const float*)d_in[6];
    const float* W2  = (const float*)d_in[7];
    const float* b2  = (const float*)d_in[8];
    const float* W3  = (const float*)d_in[9];
    const float* b3  = (const float*)d_in[10];
    float*       out = (float*)d_out;

    char*      ws    = (char*)d_ws;
    float4*    vtx4  = (float4*)(ws + VTX4_OFF);
    int*       kidx  = (int*)(ws + KIDX_OFF);
    float*     kw    = (float*)(ws + KW_OFF);
    _Float16*  wfrag = (_Float16*)(ws + WFRAG_OFF);

    hipLaunchKernelGGL(prep_kernel, dim3(27), dim3(256), 0, stream, vtx, vtx4);
    hipLaunchKernelGGL(knn_kernel, dim3(NQ / 64 + 52), dim3(1024), 0, stream,
                       vtx4, qp, kidx, kw, W0, W1, W2, W3, wfrag);
    hipLaunchKernelGGL(mlp_kernel, dim3(NQ * 8 / 128), dim3(256), 0, stream,
                       vf, vtx4, qp, kidx, kw, wfrag, b0, b1, b2, b3, out);
}

// Round 22
// 151.881 us; speedup vs baseline: 1.0339x; 1.0339x over previous
//
#include <hip/hip_runtime.h>
#include <hip/hip_fp16.h>

#define NV    6890
#define NQ    32768
#define DF    64
#define NW    16      // waves per knn block
#define CHUNK 431     // ceil(NV/16)
#define SAMP  32      // sample vertices per wave (16*32 = 512 total)
#define CAPQ  20

typedef _Float16 v8h  __attribute__((ext_vector_type(8)));
typedef float    f32x4 __attribute__((ext_vector_type(4)));
typedef unsigned int       u32;
typedef unsigned long long u64;
typedef unsigned short     u16;

// ---- workspace layout (bytes) ----
static constexpr size_t VTX4_OFF  = 0;                               // float4[6912]
static constexpr size_t KIDX_OFF  = 110592;                          // int[NQ*8]
static constexpr size_t KW_OFF    = KIDX_OFF + (size_t)NQ * 8 * 4;   // float[NQ*8]
static constexpr size_t WFRAG_OFF = KW_OFF + (size_t)NQ * 8 * 4;     // f16[53248]

__device__ __forceinline__ u32 monof(float s) {
    u32 u = __float_as_uint(s);
    return (u & 0x80000000u) ? ~u : (u | 0x80000000u);
}

// Force an index into an SGPR so vtx4[.] compiles to s_load (wave-uniform by
// construction: the value is identical across lanes when called).
__device__ __forceinline__ int sgpr(int j) {
    return __builtin_amdgcn_readfirstlane(j);
}

// distance-only sorted top-8 insert (ascending), ~24 VALU.
#define DINSERT(sv) do {                                               \
    bool c0 = (sv) < dbest[0], c1 = (sv) < dbest[1],                   \
         c2 = (sv) < dbest[2], c3 = (sv) < dbest[3],                   \
         c4 = (sv) < dbest[4], c5 = (sv) < dbest[5],                   \
         c6 = (sv) < dbest[6], c7 = (sv) < dbest[7];                   \
    dbest[7] = c7 ? (c6 ? dbest[6] : (sv)) : dbest[7];                 \
    dbest[6] = c6 ? (c5 ? dbest[5] : (sv)) : dbest[6];                 \
    dbest[5] = c5 ? (c4 ? dbest[4] : (sv)) : dbest[5];                 \
    dbest[4] = c4 ? (c3 ? dbest[3] : (sv)) : dbest[4];                 \
    dbest[3] = c3 ? (c2 ? dbest[2] : (sv)) : dbest[3];                 \
    dbest[2] = c2 ? (c1 ? dbest[1] : (sv)) : dbest[2];                 \
    dbest[1] = c1 ? (c0 ? dbest[0] : (sv)) : dbest[1];                 \
    dbest[0] = c0 ? (sv) : dbest[0];                                   \
} while (0)

// u64 sorted top-8 insert (ascending). Compares precomputed; uses OLD values.
#define KINSERT(nk) do {                                  \
    bool c0 = (nk) < key[0], c1 = (nk) < key[1],          \
         c2 = (nk) < key[2], c3 = (nk) < key[3],          \
         c4 = (nk) < key[4], c5 = (nk) < key[5],          \
         c6 = (nk) < key[6], c7 = (nk) < key[7];          \
    key[7] = c7 ? (c6 ? key[6] : (nk)) : key[7];          \
    key[6] = c6 ? (c5 ? key[5] : (nk)) : key[6];          \
    key[5] = c5 ? (c4 ? key[4] : (nk)) : key[5];          \
    key[4] = c4 ? (c3 ? key[3] : (nk)) : key[4];          \
    key[3] = c3 ? (c2 ? key[2] : (nk)) : key[3];          \
    key[2] = c2 ? (c1 ? key[1] : (nk)) : key[2];          \
    key[1] = c1 ? (c0 ? key[0] : (nk)) : key[1];          \
    key[0] = c0 ? (nk) : key[0];                          \
} while (0)

#define TRYQ(sv, jv) do {                                                      \
    if ((sv) <= T) {                                                           \
        if (cnt < CAPQ) { qq[w][l][cnt] = (u16)(jv); ++cnt; }                  \
        else {                                                                 \
            u64 nk = ((u64)monof(sv) << 16) | (u64)(jv);                       \
            if (nk < key[7]) { KINSERT(nk); }                                  \
        }                                                                      \
    }                                                                          \
} while (0)

// prep: pack vertices {x,y,z,0.5|v|^2} only (wfrag fused into knn grid).
__global__ void prep_kernel(const float* __restrict__ vtx, float4* __restrict__ vtx4) {
    int i = blockIdx.x * 256 + threadIdx.x;
    if (i < NV) {
        float x = vtx[i * 3 + 0], y = vtx[i * 3 + 1], z = vtx[i * 3 + 2];
        vtx4[i] = make_float4(x, y, z, 0.5f * (x * x + y * y + z * z));
    }
}

__device__ __forceinline__ float vdist(const float4 v, float nqx, float nqy, float nqz) {
    float s = fmaf(nqx, v.x, v.w);
    s = fmaf(nqy, v.y, s);
    return fmaf(nqz, v.z, s);
}

// Exact two-phase KNN (R20 champion: SGPR-forced scalar addressing).
// Block = 64 queries (1/lane) x 16 waves; blocks >= 512 do the wfrag swizzle.
// Phase A: distance-only top-8 over 32-vertex sample slice -> LDS tree reduce
//   -> exact T = 8th smallest of 512-sample.
// Scan: chunk of 431, unroll-4 SGPR-addressed s_load float4s, nested-branch
//   queue append (cap 20; overflow -> inline exact u64-key insert).
// Drain: batches of 4 (per-lane loads), exact u64 keys = (monotone(s)<<16)|idx
//   (reproduces top_k (distance,index) order). Merge: log2 tree over 16 lists.
__global__ __launch_bounds__(1024, 8) void knn_kernel(const float4* __restrict__ vtx4,
                                                      const float* __restrict__ qpts,
                                                      int* __restrict__ kidx,
                                                      float* __restrict__ kw,
                                                      const float* __restrict__ W0,
                                                      const float* __restrict__ W1,
                                                      const float* __restrict__ W2,
                                                      const float* __restrict__ W3,
                                                      _Float16* __restrict__ wfrag) {
    if (blockIdx.x >= NQ / 64) {
        // ---- fused weight-fragment swizzle: tile t=kt*NCT+ct, elem=
        // t*512+lane*8+jj, k=kt*32+(lane>>4)*8+jj, col=ct*16+(lane&15) ----
        int e = (blockIdx.x - NQ / 64) * 1024 + threadIdx.x;   // 0..53247
        const float* W; int base, NCT, C, KD;
        if      (e < 12288) { W = W0; base = 0;     NCT = 8; C = 128; KD = 67;  }
        else if (e < 28672) { W = W1; base = 12288; NCT = 8; C = 128; KD = 128; }
        else if (e < 45056) { W = W2; base = 28672; NCT = 8; C = 128; KD = 128; }
        else                { W = W3; base = 45056; NCT = 4; C = 64;  KD = 128; }
        int le = e - base;
        int t = le >> 9, r = le & 511;
        int lane = r >> 3, jj = r & 7;
        int kt = t / NCT, ct = t % NCT;
        int k = kt * 32 + (lane >> 4) * 8 + jj;
        int col = ct * 16 + (lane & 15);
        float v = (k < KD) ? W[k * C + col] : 0.0f;
        wfrag[e] = (_Float16)v;
        return;
    }

    __shared__ u64   kbuf[8][64][9];        // 36864 B; aliased f32[16][64][9] in phase A
    __shared__ u16   qq[NW][64][CAPQ];      // 40960 B
    __shared__ float Tbc[64];
    float (*fbuf)[64][9] = (float (*)[64][9])kbuf;

    const int tid = threadIdx.x, w = tid >> 6, l = tid & 63;
    const int m = blockIdx.x * 64 + l;
    const float qx = qpts[m * 3 + 0], qy = qpts[m * 3 + 1], qz = qpts[m * 3 + 2];
    const float nqx = -qx, nqy = -qy, nqz = -qz;

    // ---- phase A: per-wave 32-vertex sample, distance-only top-8 ----
    float dbest[8];
#pragma unroll
    for (int i = 0; i < 8; ++i) dbest[i] = 3.0e38f;
    {
        const int s0 = sgpr(w * SAMP);
#pragma unroll 4
        for (int j = 0; j < SAMP; ++j) {
            float s = vdist(vtx4[s0 + j], nqx, nqy, nqz);   // SGPR addr -> s_load
            DINSERT(s);
        }
    }
#pragma unroll
    for (int i = 0; i < 8; ++i) fbuf[w][l][i] = dbest[i];
    __syncthreads();

    // ---- T tree-reduce: read [st,2st) slots, merge, write [0,st) ----
#pragma unroll 1
    for (int st = 8; st >= 1; st >>= 1) {
        if (w < st) {
#pragma unroll
            for (int e = 0; e < 8; ++e) {
                float s = fbuf[w + st][l][e];
                if (s < dbest[7]) { DINSERT(s); }
            }
            if (st > 1) {
#pragma unroll
                for (int i = 0; i < 8; ++i) fbuf[w][l][i] = dbest[i];
            }
        }
        __syncthreads();
    }
    if (w == 0) Tbc[l] = dbest[7];
    __syncthreads();
    const float T = Tbc[l];

    // ---- scan: full chunk, unroll-4, SGPR-addressed loads ----
    u64 key[8];
#pragma unroll
    for (int i = 0; i < 8; ++i) key[i] = ~0ull;
    u32 cnt = 0;
    const int j0 = sgpr(w * CHUNK);
    const int j1 = sgpr((w * CHUNK + CHUNK < NV) ? w * CHUNK + CHUNK : NV);
    {
        int j = j0;
#pragma unroll 1
        for (; j + 4 <= j1; j += 4) {
            const int jb = sgpr(j);
            float4 v0 = vtx4[jb + 0], v1 = vtx4[jb + 1];
            float4 v2 = vtx4[jb + 2], v3 = vtx4[jb + 3];
            float s0 = vdist(v0, nqx, nqy, nqz);
            float s1 = vdist(v1, nqx, nqy, nqz);
            float s2 = vdist(v2, nqx, nqy, nqz);
            float s3 = vdist(v3, nqx, nqy, nqz);
            TRYQ(s0, jb + 0); TRYQ(s1, jb + 1); TRYQ(s2, jb + 2); TRYQ(s3, jb + 3);
        }
        for (; j < j1; ++j) {
            const int jb = sgpr(j);
            float s = vdist(vtx4[jb], nqx, nqy, nqz);
            TRYQ(s, jb);
        }
    }

    // ---- drain queue in batches of 4 (exact keys, per-lane loads) ----
#pragma unroll 1
    for (int b = 0; b < CAPQ; b += 4) {
        if (!__any(cnt > (u32)b)) break;
        u32 jj[4]; float4 vv[4];
#pragma unroll
        for (int t = 0; t < 4; ++t) {
            u32 qi = ((u32)(b + t) < cnt) ? (u32)qq[w][l][b + t] : 0u;
            jj[t] = qi; vv[t] = vtx4[qi];
        }
#pragma unroll
        for (int t = 0; t < 4; ++t) {
            float s = vdist(vv[t], nqx, nqy, nqz);
            u64 nk = ((u64)monof(s) << 16) | (u64)jj[t];
            nk = ((u32)(b + t) < cnt) ? nk : ~0ull;
            if (nk < key[7]) { KINSERT(nk); }
        }
    }

    // ---- tree merge of 16 key lists: publish [st,2st) -> merge on [0,st) ----
#pragma unroll 1
    for (int st = 8; st >= 1; st >>= 1) {
        if (w >= st && w < 2 * st) {
#pragma unroll
            for (int i = 0; i < 8; ++i) kbuf[w - st][l][i] = key[i];
        }
        __syncthreads();
        if (w < st) {
#pragma unroll
            for (int e = 0; e < 8; ++e) {
                u64 nk = kbuf[w][l][e];
                if (nk < key[7]) { KINSERT(nk); }
            }
        }
        __syncthreads();
    }

    // ---- wave 0: weights + output ----
    if (w == 0) {
        float q2 = fmaf(qx, qx, fmaf(qy, qy, qz * qz));
        float inv[8], ssum = 0.0f;
        int idx8[8];
#pragma unroll
        for (int i = 0; i < 8; ++i) {
            u32 us = (u32)(key[i] >> 16);
            u32 uo = (us & 0x80000000u) ? (us & 0x7FFFFFFFu) : ~us;
            float s = __uint_as_float(uo);
            float dd = fmaf(2.0f, s, q2);
            float d = sqrtf(fmaxf(dd, 0.0f)) + 1e-9f;
            inv[i] = 1.0f / d; ssum += inv[i];
            idx8[i] = (int)(key[i] & 0xFFFFull);
        }
        float rs = 1.0f / ssum;
#pragma unroll
        for (int i = 0; i < 8; ++i) {
            kidx[m * 8 + i] = idx8[i];
            kw[m * 8 + i]   = inv[i] * rs;
        }
    }
}

// One MLP layer on this wave's 32 rows, in-place in buf. A-frag: row=l&15(+16*rt),
// k=(l>>4)*8+j; B-frag preswizzled with the SAME (lane,j)->k map (k-perm cancels).
template <int KSTEPS, int NCT, bool RELU>
__device__ __forceinline__ void mlp_layer(_Float16 (*buf)[136],
                                          const _Float16* __restrict__ frag,
                                          const float* __restrict__ bias,
                                          int w, int l) {
    const int cl = l & 15, gl = l >> 4;
    f32x4 acc[2][NCT];
#pragma unroll
    for (int ct = 0; ct < NCT; ++ct) {
        float bv = bias[ct * 16 + cl];
#pragma unroll
        for (int rt = 0; rt < 2; ++rt) acc[rt][ct] = (f32x4){bv, bv, bv, bv};
    }
    const _Float16* fb = frag + (size_t)l * 8;
#pragma unroll 1
    for (int ks = 0; ks < KSTEPS; ++ks) {
        v8h a0 = *(const v8h*)&buf[w * 32 + cl][ks * 32 + gl * 8];
        v8h a1 = *(const v8h*)&buf[w * 32 + 16 + cl][ks * 32 + gl * 8];
#pragma unroll
        for (int ct = 0; ct < NCT; ++ct) {
            v8h bf = *(const v8h*)(fb + (size_t)(ks * NCT + ct) * 512);
            acc[0][ct] = __builtin_amdgcn_mfma_f32_16x16x32_f16(a0, bf, acc[0][ct], 0, 0, 0);
            acc[1][ct] = __builtin_amdgcn_mfma_f32_16x16x32_f16(a1, bf, acc[1][ct], 0, 0, 0);
        }
    }
    // C/D layout (m89-verified): row=(l>>4)*4+j, col=l&15
#pragma unroll
    for (int rt = 0; rt < 2; ++rt)
#pragma unroll
        for (int ct = 0; ct < NCT; ++ct)
#pragma unroll
            for (int j = 0; j < 4; ++j) {
                float v = acc[rt][ct][j];
                if (RELU) v = fmaxf(v, 0.0f);
                buf[w * 32 + rt * 16 + gl * 4 + j][ct * 16 + cl] = (_Float16)v;
            }
}

// Block = 128 rows (16 queries x 8 NB), 4 waves, each wave owns 32 rows.
// No __syncthreads anywhere: all LDS traffic is wave-private.
__global__ __launch_bounds__(256, 3) void mlp_kernel(
    const float* __restrict__ vf, const float4* __restrict__ vtx4,
    const float* __restrict__ qpts,
    const int* __restrict__ kidx, const float* __restrict__ kw,
    const _Float16* __restrict__ wfrag,
    const float* __restrict__ b0, const float* __restrict__ b1,
    const float* __restrict__ b2, const float* __restrict__ b3,
    float* __restrict__ out) {
    __shared__ _Float16 buf[128][136];   // 34.8 KB, stride 136 -> b128 reads 2-way (free)
    const int tid = threadIdx.x, w = tid >> 6, l = tid & 63;
    {
        int h = l & 1;
        int lrow = w * 32 + (l >> 1);
        int grow = blockIdx.x * 128 + lrow;
        int q = grow >> 3;
        int idx = kidx[grow];
        const float4* src = (const float4*)(vf + (size_t)idx * DF) + h * 8;
#pragma unroll
        for (int t = 0; t < 4; ++t) {
            float4 a = src[2 * t], b = src[2 * t + 1];
            v8h pk = {(_Float16)a.x, (_Float16)a.y, (_Float16)a.z, (_Float16)a.w,
                      (_Float16)b.x, (_Float16)b.y, (_Float16)b.z, (_Float16)b.w};
            *(v8h*)&buf[lrow][h * 32 + t * 8] = pk;
        }
        v8h zz = {0, 0, 0, 0, 0, 0, 0, 0};
        if (h == 0) {
            float4 v = vtx4[idx];
            float qx = qpts[q * 3 + 0], qy = qpts[q * 3 + 1], qz = qpts[q * 3 + 2];
            v8h d = {(_Float16)(qx - v.x), (_Float16)(qy - v.y), (_Float16)(qz - v.z),
                     0, 0, 0, 0, 0};
            *(v8h*)&buf[lrow][64] = d;
            *(v8h*)&buf[lrow][88] = zz;
        } else {
            *(v8h*)&buf[lrow][72] = zz;
            *(v8h*)&buf[lrow][80] = zz;
        }
    }

    mlp_layer<3, 8, true>(buf, wfrag + 0,     b0, w, l);
    mlp_layer<4, 8, true>(buf, wfrag + 12288, b1, w, l);
    mlp_layer<4, 8, true>(buf, wfrag + 28672, b2, w, l);

    // ---- layer 3 (K=128 -> 64 cols) + inverse-distance weighting + 8-row reduce ----
    {
        const int cl = l & 15, gl = l >> 4;
        f32x4 acc[2][4];
#pragma unroll
        for (int ct = 0; ct < 4; ++ct) {
            float bv = b3[ct * 16 + cl];
#pragma unroll
            for (int rt = 0; rt < 2; ++rt) acc[rt][ct] = (f32x4){bv, bv, bv, bv};
        }
        const _Float16* fb = wfrag + 45056 + (size_t)l * 8;
#pragma unroll 1
        for (int ks = 0; ks < 4; ++ks) {
            v8h a0 = *(const v8h*)&buf[w * 32 + cl][ks * 32 + gl * 8];
            v8h a1 = *(const v8h*)&buf[w * 32 + 16 + cl][ks * 32 + gl * 8];
#pragma unroll
            for (int ct = 0; ct < 4; ++ct) {
                v8h bf = *(const v8h*)(fb + (size_t)(ks * 4 + ct) * 512);
                acc[0][ct] = __builtin_amdgcn_mfma_f32_16x16x32_f16(a0, bf, acc[0][ct], 0, 0, 0);
                acc[1][ct] = __builtin_amdgcn_mfma_f32_16x16x32_f16(a1, bf, acc[1][ct], 0, 0, 0);
            }
        }
        int GRbase = blockIdx.x * 128 + w * 32;
#pragma unroll
        for (int rt = 0; rt < 2; ++rt) {
            int r4 = GRbase + rt * 16 + gl * 4;
            float4 kv = *(const float4*)&kw[r4];
#pragma unroll
            for (int ct = 0; ct < 4; ++ct) {
                float v = acc[rt][ct][0] * kv.x + acc[rt][ct][1] * kv.y +
                          acc[rt][ct][2] * kv.z + acc[rt][ct][3] * kv.w;
                v += __shfl_xor(v, 16);
                if ((gl & 1) == 0) {
                    int q = (GRbase + rt * 16 + ((gl == 2) ? 8 : 0)) >> 3;
                    out[(size_t)q * 64 + ct * 16 + cl] = v;
                }
            }
        }
    }
}

extern "C" void kernel_launch(void* const* d_in, const int* in_sizes, int n_in,
                              void* d_out, int out_size, void* d_ws, size_t ws_size,
                              hipStream_t stream) {
    const float* vtx = (const float*)d_in[0];
    const float* vf  = (const float*)d_in[1];
    const float* qp  = (const float*)d_in[2];
    const float* W0  = (const float*)d_in[3];
    const float* b0  = (const float*)d_in[4];
    const float* W1  = (const float*)d_in[5];
    const float* b1  = (const float*)d_in[6];
    const float* W2  = (const float*)d_in[7];
    const float* b2  = (const float*)d_in[8];
    const float* W3  = (const float*)d_in[9];
    const float* b3  = (const float*)d_in[10];
    float*       out = (float*)d_out;

    char*      ws    = (char*)d_ws;
    float4*    vtx4  = (float4*)(ws + VTX4_OFF);
    int*       kidx  = (int*)(ws + KIDX_OFF);
    float*     kw    = (float*)(ws + KW_OFF);
    _Float16*  wfrag = (_Float16*)(ws + WFRAG_OFF);

    hipLaunchKernelGGL(prep_kernel, dim3(27), dim3(256), 0, stream, vtx, vtx4);
    hipLaunchKernelGGL(knn_kernel, dim3(NQ / 64 + 52), dim3(1024), 0, stream,
                       vtx4, qp, kidx, kw, W0, W1, W2, W3, wfrag);
    hipLaunchKernelGGL(mlp_kernel, dim3(NQ * 8 / 128), dim3(256), 0, stream,
                       vf, vtx4, qp, kidx, kw, wfrag, b0, b1, b2, b3, out);
}